// Round 1
// baseline (789.692 us; speedup 1.0000x reference)
//
#include <hip/hip_runtime.h>
#include <hip/hip_bf16.h>
#include <math.h>

#define NEG_SLOPE 0.2f

// ============================ CSR build =====================================
__global__ void init_kernel(int* counts, int* gstart, int* gend, int n, int b){
  int i = blockIdx.x*blockDim.x + threadIdx.x;
  if (i < n) counts[i] = 0;
  if (i < b){ gstart[i] = n; gend[i] = 0; }
}

__global__ void build_kernel(const int* __restrict__ ei, const int* __restrict__ batch,
                             int* counts, int* gstart, int* gend, int E, int n){
  int i = blockIdx.x*blockDim.x + threadIdx.x;
  if (i < E) atomicAdd(&counts[ei[E+i]], 1);
  if (i < n){
    int b = batch[i];
    atomicMin(&gstart[b], i);
    atomicMax(&gend[b], i+1);
  }
}

__global__ void scan_kernel(const int* __restrict__ counts, int* offs, int* cursor, int n){
  const int T = 1024;
  int tid = threadIdx.x;
  int chunk = (n + T - 1)/T;
  int base = tid*chunk;
  int local = 0;
  for (int i=0;i<chunk;i++){ int idx=base+i; if (idx<n) local += counts[idx]; }
  __shared__ int ss[T];
  ss[tid]=local; __syncthreads();
  for (int off=1; off<T; off<<=1){
    int v = (tid>=off)? ss[tid-off] : 0;
    __syncthreads();
    ss[tid]+=v;
    __syncthreads();
  }
  int run = ss[tid]-local;  // exclusive prefix
  for (int i=0;i<chunk;i++){
    int idx=base+i;
    if (idx<n){ offs[idx]=run; cursor[idx]=run; run += counts[idx]; }
  }
  if (tid==T-1) offs[n]=run;
}

__global__ void fill_kernel(const int* __restrict__ ei, int* cursor, int* csr, int E){
  int i = blockIdx.x*blockDim.x + threadIdx.x;
  if (i<E){
    int dst = ei[E+i];
    int pos = atomicAdd(&cursor[dst],1);
    csr[pos] = ei[i];
  }
}

// ============================ fp32 tiled GEMM ===============================
// C[M,N] = A[M,K] @ B[K,N], row-major. BM=BN=64, BK=16, 256 threads, 4x4/thread.
__global__ __launch_bounds__(256) void gemm64(const float* __restrict__ A,
                                              const float* __restrict__ B,
                                              float* __restrict__ C,
                                              int M, int K, int N){
  __shared__ float As[16][64];
  __shared__ float Bs[16][64];
  int tid = threadIdx.x;
  int bm = blockIdx.x*64, bn = blockIdx.y*64;
  int aRow = tid>>2;            // 0..63
  int aK   = (tid&3)*4;         // 0,4,8,12
  int bRow = tid>>4;            // 0..15
  int bCol = (tid&15)*4;        // 0..60
  int ty = tid>>4, tx = tid&15;
  float acc[4][4] = {};
  for (int k0=0; k0<K; k0+=16){
    float4 av = make_float4(0.f,0.f,0.f,0.f);
    if (bm+aRow < M) av = *reinterpret_cast<const float4*>(A + (size_t)(bm+aRow)*K + k0 + aK);
    float4 bv = *reinterpret_cast<const float4*>(B + (size_t)(k0+bRow)*N + bn + bCol);
    As[aK+0][aRow]=av.x; As[aK+1][aRow]=av.y; As[aK+2][aRow]=av.z; As[aK+3][aRow]=av.w;
    *reinterpret_cast<float4*>(&Bs[bRow][bCol]) = bv;
    __syncthreads();
    #pragma unroll
    for (int kk=0; kk<16; kk++){
      float a0=As[kk][ty*4+0], a1=As[kk][ty*4+1], a2=As[kk][ty*4+2], a3=As[kk][ty*4+3];
      float b0=Bs[kk][tx*4+0], b1=Bs[kk][tx*4+1], b2=Bs[kk][tx*4+2], b3=Bs[kk][tx*4+3];
      acc[0][0]+=a0*b0; acc[0][1]+=a0*b1; acc[0][2]+=a0*b2; acc[0][3]+=a0*b3;
      acc[1][0]+=a1*b0; acc[1][1]+=a1*b1; acc[1][2]+=a1*b2; acc[1][3]+=a1*b3;
      acc[2][0]+=a2*b0; acc[2][1]+=a2*b1; acc[2][2]+=a2*b2; acc[2][3]+=a2*b3;
      acc[3][0]+=a3*b0; acc[3][1]+=a3*b1; acc[3][2]+=a3*b2; acc[3][3]+=a3*b3;
    }
    __syncthreads();
  }
  #pragma unroll
  for (int i=0;i<4;i++){
    int row = bm + ty*4 + i;
    if (row < M){
      float4 v = make_float4(acc[i][0],acc[i][1],acc[i][2],acc[i][3]);
      *reinterpret_cast<float4*>(C + (size_t)row*N + bn + tx*4) = v;
    }
  }
}

// ============== per-node attention logits s,d = <h, a_src/a_dst> ============
template<int H, int C>
__global__ void sd_kernel(const float* __restrict__ h, const float* __restrict__ asrc,
                          const float* __restrict__ adst, float* __restrict__ s,
                          float* __restrict__ d, int n_nodes){
  int wave = threadIdx.x >> 6, lane = threadIdx.x & 63;
  int n = blockIdx.x*4 + wave;
  if (n >= n_nodes) return;
  const float* hn = h + (size_t)n*H*C;
  #pragma unroll
  for (int hd=0; hd<H; ++hd){
    float ps=0.f, pd=0.f;
    for (int c=lane; c<C; c+=64){
      float v = hn[hd*C+c];
      ps += v*asrc[hd*C+c];
      pd += v*adst[hd*C+c];
    }
    #pragma unroll
    for (int off=32; off; off>>=1){ ps += __shfl_down(ps,off); pd += __shfl_down(pd,off); }
    if (lane==0){ s[n*H+hd]=ps; d[n*H+hd]=pd; }
  }
}

// ================= GAT aggregation: softmax over in-edges ====================
// One block per dst node. Self-loop handled as a virtual extra edge.
// y[n] = elu( (sum_e w_e * h[src_e]) / (sum_e w_e + 1e-16) + bias ),
// w_e = exp(leakyrelu(s[src]+d[dst]) - max).
template<int H, int C>
__global__ __launch_bounds__(256) void agg_kernel(
    const float* __restrict__ hbuf, const float* __restrict__ s,
    const float* __restrict__ d, const int* __restrict__ offs,
    const int* __restrict__ csr, const float* __restrict__ bias,
    float* __restrict__ y, int n_nodes){
  constexpr int HC = H*C;
  int n = blockIdx.x;
  int tid = threadIdx.x;
  __shared__ float sdst[H];
  __shared__ float sm[H];
  __shared__ float sl[H];
  __shared__ float wred[4*H];
  __shared__ float sw[64*H];
  __shared__ int ssrc[64];
  if (tid < H) sdst[tid] = d[n*H+tid];
  int start = offs[n];
  int cnt = offs[n+1]-start;
  int cnt1 = cnt+1;                      // + self loop
  __syncthreads();
  // phase 1: per-head max of leakyrelu(s[src]+d[dst])
  float mx[H];
  #pragma unroll
  for (int h=0;h<H;h++) mx[h] = -1e30f;
  for (int i=tid; i<cnt1; i+=256){
    int src = (i==cnt) ? n : csr[start+i];
    #pragma unroll
    for (int h=0;h<H;h++){
      float e = s[src*H+h] + sdst[h];
      e = e>=0.f ? e : NEG_SLOPE*e;
      mx[h] = fmaxf(mx[h], e);
    }
  }
  #pragma unroll
  for (int off=32; off; off>>=1)
    #pragma unroll
    for (int h=0;h<H;h++) mx[h] = fmaxf(mx[h], __shfl_down(mx[h],off));
  int wave = tid>>6, lane = tid&63;
  if (lane==0)
    #pragma unroll
    for (int h=0;h<H;h++) wred[wave*H+h]=mx[h];
  __syncthreads();
  if (tid < H){
    float m = wred[tid];
    for (int w=1;w<4;w++) m = fmaxf(m, wred[w*H+tid]);
    sm[tid]=m;
  }
  __syncthreads();
  // phase 2: weighted accumulate, 64-edge chunks
  float acc = 0.f;
  float lp[H];
  #pragma unroll
  for (int h=0;h<H;h++) lp[h]=0.f;
  int c = tid;
  int head = (tid < HC) ? (c / C) : 0;
  for (int base=0; base<cnt1; base+=64){
    int nchunk = min(64, cnt1-base);
    if (tid < nchunk){
      int i = base+tid;
      int src = (i==cnt) ? n : csr[start+i];
      ssrc[tid]=src;
      #pragma unroll
      for (int h=0;h<H;h++){
        float e = s[src*H+h] + sdst[h];
        e = e>=0.f ? e : NEG_SLOPE*e;
        float w = expf(e - sm[h]);
        sw[tid*H+h]=w;
        lp[h]+=w;
      }
    }
    __syncthreads();
    if (tid < HC){
      for (int j=0;j<nchunk;j++){
        acc += sw[j*H+head] * hbuf[(size_t)ssrc[j]*HC + c];
      }
    }
    __syncthreads();
  }
  if (wave==0){
    #pragma unroll
    for (int off=32; off; off>>=1)
      #pragma unroll
      for (int h=0;h<H;h++) lp[h] += __shfl_down(lp[h],off);
    if (lane==0)
      #pragma unroll
      for (int h=0;h<H;h++) sl[h]=lp[h];
  }
  __syncthreads();
  if (tid < HC){
    float o = acc/(sl[head]+1e-16f) + bias[c];
    y[(size_t)n*HC+c] = o>0.f ? o : expm1f(o);
  }
}

// ============ Set2Set (3 steps) + gf-MLP + scorer, one block/graph ==========
__global__ __launch_bounds__(256) void set2set_mlp_kernel(
    const float* __restrict__ x,            // [N,128]
    const int* __restrict__ gstart, const int* __restrict__ gend,
    const float* __restrict__ Wih, const float* __restrict__ Whh,
    const float* __restrict__ bih, const float* __restrict__ bhh,
    const float* __restrict__ gfeat,
    const float* __restrict__ gW1, const float* __restrict__ gb1,
    const float* __restrict__ gW2, const float* __restrict__ gb2,
    const float* __restrict__ mW1, const float* __restrict__ mb1,
    const float* __restrict__ mW2, const float* __restrict__ mb2,
    float* __restrict__ e_ws, float* __restrict__ out){
  int b = blockIdx.x;
  int tid = threadIdx.x;
  __shared__ float qstar[256], hL[128], cL[128], gates[512], q[128], r[128];
  __shared__ float red[256];
  __shared__ float z[288], hid[128], gf1[64];
  int start = gstart[b], end = gend[b];
  qstar[tid]=0.f;
  if (tid<128){ hL[tid]=0.f; cL[tid]=0.f; }
  __syncthreads();
  for (int step=0; step<3; ++step){
    // gates = qstar @ Wih.T + bih + h @ Whh.T + bhh
    for (int j=tid; j<512; j+=256){
      float g = bih[j] + bhh[j];
      const float* wi = Wih + (size_t)j*256;
      for (int k=0;k<256;k++) g += qstar[k]*wi[k];
      const float* wh = Whh + (size_t)j*128;
      for (int k=0;k<128;k++) g += hL[k]*wh[k];
      gates[j]=g;
    }
    __syncthreads();
    if (tid<128){
      float ig = 1.f/(1.f+expf(-gates[tid]));
      float fg = 1.f/(1.f+expf(-gates[128+tid]));
      float gg = tanhf(gates[256+tid]);
      float og = 1.f/(1.f+expf(-gates[384+tid]));
      float c2 = fg*cL[tid] + ig*gg;
      cL[tid]=c2;
      float h2 = og*tanhf(c2);
      hL[tid]=h2; q[tid]=h2;
    }
    __syncthreads();
    // e_i = <x_i, q>, max
    float localmax = -1e30f;
    for (int i=start+tid; i<end; i+=256){
      const float* xi = x + (size_t)i*128;
      float e=0.f;
      for (int k=0;k<128;k++) e += xi[k]*q[k];
      e_ws[i]=e;
      localmax = fmaxf(localmax, e);
    }
    red[tid]=localmax; __syncthreads();
    for (int off=128; off; off>>=1){ if (tid<off) red[tid]=fmaxf(red[tid],red[tid+off]); __syncthreads(); }
    float m = red[0];
    __syncthreads();
    // w_i = exp(e-m); lsum
    float ll=0.f;
    for (int i=start+tid; i<end; i+=256){
      float w = expf(e_ws[i]-m);
      e_ws[i]=w; ll+=w;
    }
    __syncthreads();
    red[tid]=ll; __syncthreads();
    for (int off=128; off; off>>=1){ if (tid<off) red[tid]+=red[tid+off]; __syncthreads(); }
    float lsum = red[0];
    __syncthreads();
    // r[c] = sum_i w_i x_i[c] / lsum
    if (tid<128){
      float rc=0.f;
      for (int i=start;i<end;i++) rc += e_ws[i]*x[(size_t)i*128+tid];
      r[tid]=rc/(lsum+1e-16f);
    }
    __syncthreads();
    if (tid<128){ qstar[tid]=q[tid]; qstar[128+tid]=r[tid]; }
    __syncthreads();
  }
  // gf MLP: relu(gfeat@gW1+gb1)@gW2+gb2  -> z[256:288]
  if (tid<64){
    float a = gb1[tid];
    for (int k=0;k<9;k++) a += gfeat[b*9+k]*gW1[k*64+tid];
    gf1[tid] = a>0.f ? a : 0.f;
  }
  z[tid] = qstar[tid];
  __syncthreads();
  if (tid<32){
    float a = gb2[tid];
    for (int k=0;k<64;k++) a += gf1[k]*gW2[k*32+tid];
    z[256+tid]=a;
  }
  __syncthreads();
  if (tid<128){
    float a = mb1[tid];
    for (int k=0;k<288;k++) a += z[k]*mW1[(size_t)k*128+tid];
    hid[tid] = a>0.f ? a : 0.f;
  }
  __syncthreads();
  if (tid<4){
    float a = mb2[tid];
    for (int k=0;k<128;k++) a += hid[k]*mW2[k*4+tid];
    out[b*4+tid]=a;
  }
}

// ================================ launch ====================================
extern "C" void kernel_launch(void* const* d_in, const int* in_sizes, int n_in,
                              void* d_out, int out_size, void* d_ws, size_t ws_size,
                              hipStream_t stream) {
  const float* x     = (const float*)d_in[0];
  const int*   ei    = (const int*)d_in[1];
  const int*   batch = (const int*)d_in[2];
  const float* gfeat = (const float*)d_in[3];
  const float* W1    = (const float*)d_in[4];
  const float* as1   = (const float*)d_in[5];
  const float* ad1   = (const float*)d_in[6];
  const float* b1    = (const float*)d_in[7];
  const float* W2    = (const float*)d_in[8];
  const float* as2   = (const float*)d_in[9];
  const float* ad2   = (const float*)d_in[10];
  const float* b2    = (const float*)d_in[11];
  const float* W3    = (const float*)d_in[12];
  const float* as3   = (const float*)d_in[13];
  const float* ad3   = (const float*)d_in[14];
  const float* b3    = (const float*)d_in[15];
  const float* Wih   = (const float*)d_in[16];
  const float* Whh   = (const float*)d_in[17];
  const float* bih   = (const float*)d_in[18];
  const float* bhh   = (const float*)d_in[19];
  const float* gW1   = (const float*)d_in[20];
  const float* gb1   = (const float*)d_in[21];
  const float* gW2   = (const float*)d_in[22];
  const float* gb2   = (const float*)d_in[23];
  const float* mW1   = (const float*)d_in[24];
  const float* mb1   = (const float*)d_in[25];
  const float* mW2   = (const float*)d_in[26];
  const float* mb2   = (const float*)d_in[27];

  const int N = in_sizes[0]/128;   // 20000
  const int E = in_sizes[1]/2;     // 320000
  const int B = in_sizes[3]/9;     // 64

  // workspace layout
  char* ws = (char*)d_ws;
  size_t off = 0;
  auto alloc = [&](size_t bytes)->char*{
    char* p = ws + off;
    off += (bytes + 255) & ~(size_t)255;
    return p;
  };
  float* hbuf   = (float*)alloc((size_t)N*256*4);
  float* ybuf1  = (float*)alloc((size_t)N*256*4);
  float* ybuf2  = (float*)alloc((size_t)N*256*4);
  float* sbuf   = (float*)alloc((size_t)N*4*4);
  float* dbuf   = (float*)alloc((size_t)N*4*4);
  float* e_ws   = (float*)alloc((size_t)N*4);
  int*   counts = (int*)alloc((size_t)N*4);
  int*   offs   = (int*)alloc((size_t)(N+1)*4);
  int*   cursor = (int*)alloc((size_t)N*4);
  int*   csr    = (int*)alloc((size_t)E*4);
  int*   gstart = (int*)alloc((size_t)B*4);
  int*   gend   = (int*)alloc((size_t)B*4);

  int gridEN = (max(E,N)+255)/256;
  // CSR + graph bounds
  init_kernel<<<(max(N,B)+255)/256, 256, 0, stream>>>(counts, gstart, gend, N, B);
  build_kernel<<<gridEN, 256, 0, stream>>>(ei, batch, counts, gstart, gend, E, N);
  scan_kernel<<<1, 1024, 0, stream>>>(counts, offs, cursor, N);
  fill_kernel<<<(E+255)/256, 256, 0, stream>>>(ei, cursor, csr, E);

  int gm = (N+63)/64;
  // ---- layer 1: x[N,128] -> h[N,256] -> y1
  gemm64<<<dim3(gm,4), 256, 0, stream>>>(x, W1, hbuf, N, 128, 256);
  sd_kernel<4,64><<<(N+3)/4, 256, 0, stream>>>(hbuf, as1, ad1, sbuf, dbuf, N);
  agg_kernel<4,64><<<N, 256, 0, stream>>>(hbuf, sbuf, dbuf, offs, csr, b1, ybuf1, N);
  // ---- layer 2: y1[N,256] -> h[N,256] -> y2
  gemm64<<<dim3(gm,4), 256, 0, stream>>>(ybuf1, W2, hbuf, N, 256, 256);
  sd_kernel<4,64><<<(N+3)/4, 256, 0, stream>>>(hbuf, as2, ad2, sbuf, dbuf, N);
  agg_kernel<4,64><<<N, 256, 0, stream>>>(hbuf, sbuf, dbuf, offs, csr, b2, ybuf2, N);
  // ---- layer 3: y2[N,256] -> h[N,128] -> y1 (reuse)
  gemm64<<<dim3(gm,2), 256, 0, stream>>>(ybuf2, W3, hbuf, N, 256, 128);
  sd_kernel<1,128><<<(N+3)/4, 256, 0, stream>>>(hbuf, as3, ad3, sbuf, dbuf, N);
  agg_kernel<1,128><<<N, 256, 0, stream>>>(hbuf, sbuf, dbuf, offs, csr, b3, ybuf1, N);
  // ---- set2set + MLPs
  set2set_mlp_kernel<<<B, 256, 0, stream>>>(ybuf1, gstart, gend, Wih, Whh, bih, bhh,
                                            gfeat, gW1, gb1, gW2, gb2,
                                            mW1, mb1, mW2, mb2, e_ws, (float*)d_out);
}